// Round 13
// baseline (91.987 us; speedup 1.0000x reference)
//
#include <hip/hip_runtime.h>
#include <hip/hip_bf16.h>

#define N     8192
#define FIN   256
#define FOUT  64
#define ALPHA 0.2f
#define KQ    8               // j-split across blocks
#define JQ    (N / KQ)        // 1024 j per block
#define TJ    256             // j per LDS tile
#define NTL   (JQ / TJ)       // 4 tiles per block
#define NSW   2               // K-steps per wave per tile
#define RB    32              // rows per block (two 16-row A-tiles)

typedef __attribute__((ext_vector_type(8))) short bf16x8;
typedef __attribute__((ext_vector_type(4))) float f32x4;
typedef __attribute__((ext_vector_type(4))) int   i32x4;

static __device__ __forceinline__ unsigned short f2bf(float x) {
    union { float f; unsigned int u; } v; v.f = x;
    unsigned int r = v.u + 0x7FFFu + ((v.u >> 16) & 1u);   // RNE
    return (unsigned short)(r >> 16);
}
static __device__ __forceinline__ float asf(unsigned int u) {
    union { unsigned int u; float f; } v; v.u = u; return v.f;
}
// masked exp(leaky_relu(f1+f2)); scores bounded (~15) -> no softmax shift needed
static __device__ __forceinline__ float wcalc(float f1v, float f2v, int a) {
    const float e = f1v + f2v;
    const float lr = fmaxf(e, ALPHA * e);
    const float w = __expf(lr);
    return (a > 0) ? w : 0.f;
}
// posted 16B/lane global->LDS copy (no VGPR return)
static __device__ __forceinline__ void gload_lds16(const int* g, int* l) {
    __builtin_amdgcn_global_load_lds(
        (const __attribute__((address_space(1))) void*)g,
        (__attribute__((address_space(3))) void*)l,
        16, 0, 0);
}
// per-row chunk permutation (bank spread for the row-scattered consume)
static __device__ __forceinline__ int rowperm(int row) {
    return ((row << 1) | (row >> 4)) & 63;
}

// ---- kernel 1: h = X@W -> hb[j/8][col][8] (MFMA B-frag layout), f1, f2 ----
__global__ __launch_bounds__(256) void k_h(
        const float* __restrict__ X, const float* __restrict__ W,
        const float* __restrict__ a1, const float* __restrict__ a2,
        unsigned short* __restrict__ hb,
        float* __restrict__ f1, float* __restrict__ f2) {
    const int lane = threadIdx.x & 63;
    const int wave = threadIdx.x >> 6;
    const int row0 = (blockIdx.x * 4 + wave) * 4;

    const f32x4* Xr[4];
    #pragma unroll
    for (int r = 0; r < 4; ++r)
        Xr[r] = (const f32x4*)(X + (size_t)(row0 + r) * FIN);

    float acc[4] = {0.f, 0.f, 0.f, 0.f};
    #pragma unroll 4
    for (int k4 = 0; k4 < FIN / 4; ++k4) {
        const float w0 = W[(k4 * 4 + 0) * FOUT + lane];
        const float w1 = W[(k4 * 4 + 1) * FOUT + lane];
        const float w2 = W[(k4 * 4 + 2) * FOUT + lane];
        const float w3 = W[(k4 * 4 + 3) * FOUT + lane];
        #pragma unroll
        for (int r = 0; r < 4; ++r) {
            const f32x4 xv = __builtin_nontemporal_load(&Xr[r][k4]);
            acc[r] = fmaf(xv.x, w0, acc[r]);
            acc[r] = fmaf(xv.y, w1, acc[r]);
            acc[r] = fmaf(xv.z, w2, acc[r]);
            acc[r] = fmaf(xv.w, w3, acc[r]);
        }
    }

    ushort4 hv;
    hv.x = f2bf(acc[0]); hv.y = f2bf(acc[1]);
    hv.z = f2bf(acc[2]); hv.w = f2bf(acc[3]);
    *(ushort4*)&hb[(size_t)(row0 >> 3) * 512 + lane * 8 + (row0 & 7)] = hv;

    const float a1v = a1[lane];
    const float a2v = a2[lane];
    #pragma unroll
    for (int r = 0; r < 4; ++r) {
        float p1 = acc[r] * a1v;
        float p2 = acc[r] * a2v;
        #pragma unroll
        for (int off = 32; off > 0; off >>= 1) {
            p1 += __shfl_down(p1, off);
            p2 += __shfl_down(p2, off);
        }
        if (lane == 0) { f1[row0 + r] = p1; f2[row0 + r] = p2; }
    }
}

// -------- kernel 2: LDS-staged 32-row MFMA attention partial sums --------
// block b: rows (b>>3)*32..+31, j-window (b&7)*1024. Two 16-row A-tiles
// share B-fragments. 32KB tile staged via posted global_load_lds, double
// buffered; epilogue reduce aliases the (dead) tile buffers.
__global__ __launch_bounds__(256, 2) void k_attn(
        const int* __restrict__ adj, const unsigned short* __restrict__ hb,
        const float* __restrict__ f1, const float* __restrict__ f2,
        float* __restrict__ part, float* __restrict__ pden) {
    __shared__ int smem[2 * RB * TJ];   // 64 KB: adj double buffer / epilogue
    __shared__ float dred[4][32];

    const int t    = threadIdx.x;
    const int lane = t & 63;
    const int wv   = t >> 6;
    const int bid  = blockIdx.x;
    const int rg   = bid >> 3;
    const int q    = bid & 7;
    const int i0   = rg * RB;
    const int r    = lane & 15;     // A-row / output col
    const int kg   = lane >> 4;     // k-group within K-step

    const float f1a = f1[i0 + r];
    const float f1b = f1[i0 + 16 + r];
    const int jb = q * JQ;
    const int prA = rowperm(r);
    const int prB = rowperm(16 + r);

    f32x4 accA[4], accB[4];
    #pragma unroll
    for (int c = 0; c < 4; ++c) {
        accA[c] = (f32x4){0.f, 0.f, 0.f, 0.f};
        accB[c] = (f32x4){0.f, 0.f, 0.f, 0.f};
    }
    float saccA = 0.f, saccB = 0.f;

    // ---- prologue: stage tile 0 (8 rows per wave, 1 KB per instruction) ----
    #pragma unroll
    for (int rr = 0; rr < 8; ++rr) {
        const int row = wv * 8 + rr;
        gload_lds16(adj + (size_t)(i0 + row) * N + jb + ((lane ^ rowperm(row)) & 63) * 4,
                    &smem[row * TJ]);
    }
    asm volatile("s_waitcnt vmcnt(0)" ::: "memory");
    __builtin_amdgcn_s_barrier();

    int buf = 0;
    for (int tt = 0; tt < NTL; ++tt) {
        const int jt = jb + tt * TJ;

        // ---- issue this tile's hb/f2 register loads FIRST (vmcnt FIFO) ----
        bf16x8 bfr[NSW][4];
        float4 fa[NSW], fb[NSW];
        #pragma unroll
        for (int ss = 0; ss < NSW; ++ss) {
            const int s = wv * NSW + ss;
            const float* f2s = f2 + jt + s * 32 + kg * 8;
            fa[ss] = *(const float4*)(f2s);
            fb[ss] = *(const float4*)(f2s + 4);
            const unsigned short* hs =
                hb + (size_t)((jt >> 3) + s * 4 + kg) * 512 + r * 8;
            bfr[ss][0] = *(const bf16x8*)(hs);
            bfr[ss][1] = *(const bf16x8*)(hs + 128);
            bfr[ss][2] = *(const bf16x8*)(hs + 256);
            bfr[ss][3] = *(const bf16x8*)(hs + 384);
        }
        __builtin_amdgcn_sched_barrier(0);

        // ---- post next tile's stages (stay in flight across consume) ----
        if (tt + 1 < NTL) {
            #pragma unroll
            for (int rr = 0; rr < 8; ++rr) {
                const int row = wv * 8 + rr;
                gload_lds16(adj + (size_t)(i0 + row) * N + jt + TJ
                                + ((lane ^ rowperm(row)) & 63) * 4,
                            &smem[(buf ^ 1) * RB * TJ + row * TJ]);
            }
            __builtin_amdgcn_sched_barrier(0);
            asm volatile("s_waitcnt vmcnt(8)" ::: "memory");  // keep 8 posted
        } else {
            asm volatile("s_waitcnt vmcnt(0)" ::: "memory");
        }
        __builtin_amdgcn_s_barrier();     // tile[buf] fully staged, regs ready

        // ---- consume: masks from LDS, weights -> bf16 A-frags -> MFMA ----
        const int* tb = &smem[buf * RB * TJ];
        #pragma unroll
        for (int ss = 0; ss < NSW; ++ss) {
            const int s = wv * NSW + ss;
            const int g0 = s * 8 + kg * 2;
            const i32x4 a0 = *(const i32x4*)&tb[r * TJ + ((g0 ^ prA) & 63) * 4];
            const i32x4 a1 = *(const i32x4*)&tb[r * TJ + (((g0 + 1) ^ prA) & 63) * 4];
            const i32x4 b0 = *(const i32x4*)&tb[(16 + r) * TJ + ((g0 ^ prB) & 63) * 4];
            const i32x4 b1 = *(const i32x4*)&tb[(16 + r) * TJ + (((g0 + 1) ^ prB) & 63) * 4];

            // ---- A-tile weights ----
            {
                const float w0 = wcalc(f1a, fa[ss].x, a0.x);
                const float w1 = wcalc(f1a, fa[ss].y, a0.y);
                const float w2 = wcalc(f1a, fa[ss].z, a0.z);
                const float w3 = wcalc(f1a, fa[ss].w, a0.w);
                const float w4 = wcalc(f1a, fb[ss].x, a1.x);
                const float w5 = wcalc(f1a, fb[ss].y, a1.y);
                const float w6 = wcalc(f1a, fb[ss].z, a1.z);
                const float w7 = wcalc(f1a, fb[ss].w, a1.w);
                union { bf16x8 v; __hip_bfloat162 h2[4]; unsigned int u[4]; } af;
                af.h2[0] = __float22bfloat162_rn(make_float2(w0, w1));
                af.h2[1] = __float22bfloat162_rn(make_float2(w2, w3));
                af.h2[2] = __float22bfloat162_rn(make_float2(w4, w5));
                af.h2[3] = __float22bfloat162_rn(make_float2(w6, w7));
                float ds = 0.f;
                #pragma unroll
                for (int u = 0; u < 4; ++u)
                    ds += asf(af.u[u] << 16) + asf(af.u[u] & 0xFFFF0000u);
                saccA += ds;
                accA[0] = __builtin_amdgcn_mfma_f32_16x16x32_bf16(af.v, bfr[ss][0], accA[0], 0, 0, 0);
                accA[1] = __builtin_amdgcn_mfma_f32_16x16x32_bf16(af.v, bfr[ss][1], accA[1], 0, 0, 0);
                accA[2] = __builtin_amdgcn_mfma_f32_16x16x32_bf16(af.v, bfr[ss][2], accA[2], 0, 0, 0);
                accA[3] = __builtin_amdgcn_mfma_f32_16x16x32_bf16(af.v, bfr[ss][3], accA[3], 0, 0, 0);
            }
            // ---- B-tile weights (same B-fragments) ----
            {
                const float w0 = wcalc(f1b, fa[ss].x, b0.x);
                const float w1 = wcalc(f1b, fa[ss].y, b0.y);
                const float w2 = wcalc(f1b, fa[ss].z, b0.z);
                const float w3 = wcalc(f1b, fa[ss].w, b0.w);
                const float w4 = wcalc(f1b, fb[ss].x, b1.x);
                const float w5 = wcalc(f1b, fb[ss].y, b1.y);
                const float w6 = wcalc(f1b, fb[ss].z, b1.z);
                const float w7 = wcalc(f1b, fb[ss].w, b1.w);
                union { bf16x8 v; __hip_bfloat162 h2[4]; unsigned int u[4]; } af;
                af.h2[0] = __float22bfloat162_rn(make_float2(w0, w1));
                af.h2[1] = __float22bfloat162_rn(make_float2(w2, w3));
                af.h2[2] = __float22bfloat162_rn(make_float2(w4, w5));
                af.h2[3] = __float22bfloat162_rn(make_float2(w6, w7));
                float ds = 0.f;
                #pragma unroll
                for (int u = 0; u < 4; ++u)
                    ds += asf(af.u[u] << 16) + asf(af.u[u] & 0xFFFF0000u);
                saccB += ds;
                accB[0] = __builtin_amdgcn_mfma_f32_16x16x32_bf16(af.v, bfr[ss][0], accB[0], 0, 0, 0);
                accB[1] = __builtin_amdgcn_mfma_f32_16x16x32_bf16(af.v, bfr[ss][1], accB[1], 0, 0, 0);
                accB[2] = __builtin_amdgcn_mfma_f32_16x16x32_bf16(af.v, bfr[ss][2], accB[2], 0, 0, 0);
                accB[3] = __builtin_amdgcn_mfma_f32_16x16x32_bf16(af.v, bfr[ss][3], accB[3], 0, 0, 0);
            }
        }
        __builtin_amdgcn_s_barrier();     // all waves done reading tile[buf]
        buf ^= 1;
    }

    // ---- denominators: lanes l, l+16, l+32, l+48 share a row ----
    saccA += __shfl_xor(saccA, 16); saccA += __shfl_xor(saccA, 32);
    saccB += __shfl_xor(saccB, 16); saccB += __shfl_xor(saccB, 32);
    if (lane < 16) { dred[wv][lane] = saccA; dred[wv][16 + lane] = saccB; }

    // ---- acc tree-reduce across waves; red buffers alias dead tile LDS ----
    f32x4* redA = (f32x4*)smem;            // 8 KB  ([2][256])
    f32x4* redB = (f32x4*)&smem[2048];     // 8 KB
    __syncthreads();
    if (wv >= 2) {
        #pragma unroll
        for (int cg = 0; cg < 4; ++cg) {
            redA[(wv - 2) * 256 + lane * 4 + cg] = accA[cg];
            redB[(wv - 2) * 256 + lane * 4 + cg] = accB[cg];
        }
    }
    __syncthreads();
    if (wv < 2) {
        #pragma unroll
        for (int cg = 0; cg < 4; ++cg) {
            accA[cg] += redA[wv * 256 + lane * 4 + cg];
            accB[cg] += redB[wv * 256 + lane * 4 + cg];
        }
    }
    __syncthreads();
    if (wv == 1) {
        #pragma unroll
        for (int cg = 0; cg < 4; ++cg) {
            redA[lane * 4 + cg] = accA[cg];
            redB[lane * 4 + cg] = accB[cg];
        }
    }
    __syncthreads();
    if (wv == 0) {
        #pragma unroll
        for (int cg = 0; cg < 4; ++cg) {
            accA[cg] += redA[lane * 4 + cg];
            accB[cg] += redB[lane * 4 + cg];
        }
        // C/D layout: col = cg*16 + r, row = kg*4 + reg (A) / +16 (B)
        #pragma unroll
        for (int cg = 0; cg < 4; ++cg)
            #pragma unroll
            for (int rr = 0; rr < 4; ++rr) {
                __builtin_nontemporal_store(accA[cg][rr],
                    &part[(size_t)bid * 2048 + (kg * 4 + rr) * FOUT + cg * 16 + r]);
                __builtin_nontemporal_store(accB[cg][rr],
                    &part[(size_t)bid * 2048 + (16 + kg * 4 + rr) * FOUT + cg * 16 + r]);
            }
        if (lane < 32)
            __builtin_nontemporal_store(
                dred[0][lane] + dred[1][lane] + dred[2][lane] + dred[3][lane],
                &pden[bid * 32 + lane]);
    }
}

// -------- kernel 3: combine KQ partials, normalize, ELU --------
__global__ __launch_bounds__(256) void k_fin(
        const float* __restrict__ part, const float* __restrict__ pden,
        float* __restrict__ out) {
    const int t   = threadIdx.x;
    const int r   = t >> 4;
    const int c4  = (t & 15) * 4;
    const int i   = blockIdx.x * 16 + r;    // output row
    const int rgb = i >> 5;
    const int ro  = i & 31;

    float vx = 0.f, vy = 0.f, vz = 0.f, vw = 0.f;
    float den = 0.f;
    #pragma unroll
    for (int p = 0; p < KQ; ++p) {
        const int b2 = rgb * KQ + p;
        const f32x4 pv = __builtin_nontemporal_load(
            (const f32x4*)&part[(size_t)b2 * 2048 + ro * FOUT + c4]);
        vx += pv.x; vy += pv.y; vz += pv.z; vw += pv.w;
        den += __builtin_nontemporal_load(&pden[b2 * 32 + ro]);
    }
    den = fmaxf(den, 1e-30f);
    const float inv = __fdividef(1.f, den);
    f32x4 o;
    const float h0 = vx * inv; o.x = (h0 > 0.f) ? h0 : (__expf(h0) - 1.f);
    const float h1 = vy * inv; o.y = (h1 > 0.f) ? h1 : (__expf(h1) - 1.f);
    const float h2 = vz * inv; o.z = (h2 > 0.f) ? h2 : (__expf(h2) - 1.f);
    const float h3 = vw * inv; o.w = (h3 > 0.f) ? h3 : (__expf(h3) - 1.f);
    __builtin_nontemporal_store(o, (f32x4*)&out[(size_t)i * FOUT + c4]);
}

extern "C" void kernel_launch(void* const* d_in, const int* in_sizes, int n_in,
                              void* d_out, int out_size, void* d_ws, size_t ws_size,
                              hipStream_t stream) {
    const float* X   = (const float*)d_in[0];
    const int*   adj = (const int*)d_in[1];
    const float* W   = (const float*)d_in[2];
    const float* a1  = (const float*)d_in[3];
    const float* a2  = (const float*)d_in[4];
    float* out = (float*)d_out;

    unsigned short* hb = (unsigned short*)d_ws;                   // 1 MB
    float* f1   = (float*)((char*)d_ws + (size_t)FOUT * N * 2);   // N floats
    float* f2   = f1 + N;                                         // N floats
    float* part = f2 + N;                                         // 2048*2048 floats
    float* pden = part + (size_t)(N / RB) * KQ * 2048;            // 2048*32 floats

    k_h   <<<N / 16, 256, 0, stream>>>(X, W, a1, a2, hb, f1, f2);
    k_attn<<<(N / RB) * KQ, 256, 0, stream>>>(adj, hb, f1, f2, part, pden);
    k_fin <<<N / 16, 256, 0, stream>>>(part, pden, out);
}

// Round 14
// 84.920 us; speedup vs baseline: 1.0832x; 1.0832x over previous
//
#include <hip/hip_runtime.h>
#include <hip/hip_bf16.h>

#define N     8192
#define FIN   256
#define FOUT  64
#define ALPHA 0.2f
#define KQ    8               // j-split across blocks
#define JQ    (N / KQ)        // 1024 j per block
#define TJ    256             // j per LDS tile
#define NTL   (JQ / TJ)       // 4 tiles per block
#define NSW   2               // K-steps per wave per tile
#define TILEI (16 * TJ)       // ints per tile buffer

typedef __attribute__((ext_vector_type(8))) short bf16x8;
typedef __attribute__((ext_vector_type(4))) float f32x4;
typedef __attribute__((ext_vector_type(4))) int   i32x4;

static __device__ __forceinline__ unsigned short f2bf(float x) {
    union { float f; unsigned int u; } v; v.f = x;
    unsigned int r = v.u + 0x7FFFu + ((v.u >> 16) & 1u);   // RNE
    return (unsigned short)(r >> 16);
}
static __device__ __forceinline__ float asf(unsigned int u) {
    union { unsigned int u; float f; } v; v.u = u; return v.f;
}
// masked exp(leaky_relu(f1+f2)); scores bounded (~15) -> no softmax shift needed
static __device__ __forceinline__ float wcalc(float f1v, float f2v, int a) {
    const float e = f1v + f2v;
    const float lr = fmaxf(e, ALPHA * e);
    const float w = __expf(lr);
    return (a > 0) ? w : 0.f;
}
// posted 16B/lane global->LDS copy (no VGPR return)
static __device__ __forceinline__ void gload_lds16(const int* g, int* l) {
    __builtin_amdgcn_global_load_lds(
        (const __attribute__((address_space(1))) void*)g,
        (__attribute__((address_space(3))) void*)l,
        16, 0, 0);
}
// per-row chunk permutation (bank spread for the row-scattered consume)
static __device__ __forceinline__ int rowperm(int row) {
    return ((row << 1) | (row >> 3)) & 63;
}

// ---- kernel 1: h = X@W -> hb[j/8][col][8] (MFMA B-frag layout), f1, f2 ----
__global__ __launch_bounds__(256) void k_h(
        const float* __restrict__ X, const float* __restrict__ W,
        const float* __restrict__ a1, const float* __restrict__ a2,
        unsigned short* __restrict__ hb,
        float* __restrict__ f1, float* __restrict__ f2) {
    const int lane = threadIdx.x & 63;
    const int wave = threadIdx.x >> 6;
    const int row0 = (blockIdx.x * 4 + wave) * 4;

    const f32x4* Xr[4];
    #pragma unroll
    for (int r = 0; r < 4; ++r)
        Xr[r] = (const f32x4*)(X + (size_t)(row0 + r) * FIN);

    float acc[4] = {0.f, 0.f, 0.f, 0.f};
    #pragma unroll 4
    for (int k4 = 0; k4 < FIN / 4; ++k4) {
        const float w0 = W[(k4 * 4 + 0) * FOUT + lane];
        const float w1 = W[(k4 * 4 + 1) * FOUT + lane];
        const float w2 = W[(k4 * 4 + 2) * FOUT + lane];
        const float w3 = W[(k4 * 4 + 3) * FOUT + lane];
        #pragma unroll
        for (int r = 0; r < 4; ++r) {
            const f32x4 xv = __builtin_nontemporal_load(&Xr[r][k4]);
            acc[r] = fmaf(xv.x, w0, acc[r]);
            acc[r] = fmaf(xv.y, w1, acc[r]);
            acc[r] = fmaf(xv.z, w2, acc[r]);
            acc[r] = fmaf(xv.w, w3, acc[r]);
        }
    }

    ushort4 hv;
    hv.x = f2bf(acc[0]); hv.y = f2bf(acc[1]);
    hv.z = f2bf(acc[2]); hv.w = f2bf(acc[3]);
    *(ushort4*)&hb[(size_t)(row0 >> 3) * 512 + lane * 8 + (row0 & 7)] = hv;

    const float a1v = a1[lane];
    const float a2v = a2[lane];
    #pragma unroll
    for (int r = 0; r < 4; ++r) {
        float p1 = acc[r] * a1v;
        float p2 = acc[r] * a2v;
        #pragma unroll
        for (int off = 32; off > 0; off >>= 1) {
            p1 += __shfl_down(p1, off);
            p2 += __shfl_down(p2, off);
        }
        if (lane == 0) { f1[row0 + r] = p1; f2[row0 + r] = p2; }
    }
}

// register-operand prefetch for one tile (hb B-frags + f2)
static __device__ __forceinline__ void load_regs(
        int jt, int wv, int kg, int r,
        const float* __restrict__ f2, const unsigned short* __restrict__ hb,
        bf16x8 (&bfr)[NSW][4], float4 (&fa)[NSW], float4 (&fb)[NSW]) {
    #pragma unroll
    for (int ss = 0; ss < NSW; ++ss) {
        const int s = wv * NSW + ss;
        const float* f2s = f2 + jt + s * 32 + kg * 8;
        fa[ss] = *(const float4*)(f2s);
        fb[ss] = *(const float4*)(f2s + 4);
        const unsigned short* hs =
            hb + (size_t)((jt >> 3) + s * 4 + kg) * 512 + r * 8;
        bfr[ss][0] = *(const bf16x8*)(hs);
        bfr[ss][1] = *(const bf16x8*)(hs + 128);
        bfr[ss][2] = *(const bf16x8*)(hs + 256);
        bfr[ss][3] = *(const bf16x8*)(hs + 384);
    }
}

// -------- kernel 2: depth-2 LDS-staged MFMA attention partial sums --------
// block b: rows (b>>3)*16..+15, j-window (b&7)*1024. Triple-buffered adj
// tiles posted 2 ahead via global_load_lds; hb/f2 regs prefetched 1 ahead;
// counted vmcnt keeps {stages(t+1), regs(t+1), stages(t+2)} in flight.
__global__ __launch_bounds__(256, 3) void k_attn(
        const int* __restrict__ adj, const unsigned short* __restrict__ hb,
        const float* __restrict__ f1, const float* __restrict__ f2,
        float* __restrict__ part, float* __restrict__ pden) {
    __shared__ int smem[3 * TILEI];   // 48 KB: 3 adj tile buffers / epilogue
    __shared__ float dred[4][16];

    const int t    = threadIdx.x;
    const int lane = t & 63;
    const int wv   = t >> 6;
    const int bid  = blockIdx.x;
    const int rg   = bid >> 3;
    const int q    = bid & 7;
    const int i0   = rg * 16;
    const int r    = lane & 15;     // A-row / output col
    const int kg   = lane >> 4;     // k-group within K-step

    const float f1v = f1[i0 + r];
    const int jb = q * JQ;
    const int pr = rowperm(r);

    f32x4 acc[4];
    #pragma unroll
    for (int c = 0; c < 4; ++c) acc[c] = (f32x4){0.f, 0.f, 0.f, 0.f};
    float sacc = 0.f;

    // ---- prologue FIFO order: stages(0), regs(0), stages(1) ----
    #pragma unroll
    for (int rr = 0; rr < 4; ++rr) {
        const int row = wv * 4 + rr;
        gload_lds16(adj + (size_t)(i0 + row) * N + jb + ((lane ^ rowperm(row)) & 63) * 4,
                    &smem[row * TJ]);
    }
    bf16x8 bcur[NSW][4], bnxt[NSW][4];
    float4 facur[NSW], fbcur[NSW], fanxt[NSW], fbnxt[NSW];
    load_regs(jb, wv, kg, r, f2, hb, bcur, facur, fbcur);
    __builtin_amdgcn_sched_barrier(0);
    #pragma unroll
    for (int rr = 0; rr < 4; ++rr) {
        const int row = wv * 4 + rr;
        gload_lds16(adj + (size_t)(i0 + row) * N + jb + TJ + ((lane ^ rowperm(row)) & 63) * 4,
                    &smem[TILEI + row * TJ]);
    }
    __builtin_amdgcn_sched_barrier(0);

    #pragma unroll
    for (int tt = 0; tt < NTL; ++tt) {
        const int jt = jb + tt * TJ;

        // ---- prefetch next tile's register operands (before stage posts) ----
        if (tt + 1 < NTL)
            load_regs(jt + TJ, wv, kg, r, f2, hb, bnxt, fanxt, fbnxt);
        __builtin_amdgcn_sched_barrier(0);

        // ---- post stages for tile t+2 ----
        if (tt + 2 < NTL) {
            #pragma unroll
            for (int rr = 0; rr < 4; ++rr) {
                const int row = wv * 4 + rr;
                gload_lds16(adj + (size_t)(i0 + row) * N + jt + 2 * TJ
                                + ((lane ^ rowperm(row)) & 63) * 4,
                            &smem[((tt + 2) % 3) * TILEI + row * TJ]);
            }
            __builtin_amdgcn_sched_barrier(0);
        }

        // ---- counted drain: leave {s(t+1), r(t+1), s(t+2)} in flight ----
        if (tt + 2 < NTL)      asm volatile("s_waitcnt vmcnt(20)" ::: "memory");
        else if (tt + 1 < NTL) asm volatile("s_waitcnt vmcnt(16)" ::: "memory");
        else                   asm volatile("s_waitcnt vmcnt(0)"  ::: "memory");
        __builtin_amdgcn_s_barrier();     // tile t staged (all waves)

        // ---- consume tile t ----
        const int* tb = &smem[(tt % 3) * TILEI];
        #pragma unroll
        for (int ss = 0; ss < NSW; ++ss) {
            const int s = wv * NSW + ss;
            const int g0 = s * 8 + kg * 2;
            const i32x4 a0 = *(const i32x4*)&tb[r * TJ + ((g0 ^ pr) & 63) * 4];
            const i32x4 a1 = *(const i32x4*)&tb[r * TJ + (((g0 + 1) ^ pr) & 63) * 4];

            const float w0 = wcalc(f1v, facur[ss].x, a0.x);
            const float w1 = wcalc(f1v, facur[ss].y, a0.y);
            const float w2 = wcalc(f1v, facur[ss].z, a0.z);
            const float w3 = wcalc(f1v, facur[ss].w, a0.w);
            const float w4 = wcalc(f1v, fbcur[ss].x, a1.x);
            const float w5 = wcalc(f1v, fbcur[ss].y, a1.y);
            const float w6 = wcalc(f1v, fbcur[ss].z, a1.z);
            const float w7 = wcalc(f1v, fbcur[ss].w, a1.w);

            union { bf16x8 v; __hip_bfloat162 h2[4]; unsigned int u[4]; } af;
            af.h2[0] = __float22bfloat162_rn(make_float2(w0, w1));
            af.h2[1] = __float22bfloat162_rn(make_float2(w2, w3));
            af.h2[2] = __float22bfloat162_rn(make_float2(w4, w5));
            af.h2[3] = __float22bfloat162_rn(make_float2(w6, w7));

            float ds = 0.f;
            #pragma unroll
            for (int u = 0; u < 4; ++u)
                ds += asf(af.u[u] << 16) + asf(af.u[u] & 0xFFFF0000u);
            sacc += ds;

            acc[0] = __builtin_amdgcn_mfma_f32_16x16x32_bf16(af.v, bcur[ss][0], acc[0], 0, 0, 0);
            acc[1] = __builtin_amdgcn_mfma_f32_16x16x32_bf16(af.v, bcur[ss][1], acc[1], 0, 0, 0);
            acc[2] = __builtin_amdgcn_mfma_f32_16x16x32_bf16(af.v, bcur[ss][2], acc[2], 0, 0, 0);
            acc[3] = __builtin_amdgcn_mfma_f32_16x16x32_bf16(af.v, bcur[ss][3], acc[3], 0, 0, 0);
        }
        __builtin_amdgcn_s_barrier();     // all waves done reading tile t

        // ---- rotate register double buffer (static, loop is unrolled) ----
        if (tt + 1 < NTL) {
            #pragma unroll
            for (int ss = 0; ss < NSW; ++ss) {
                bcur[ss][0] = bnxt[ss][0]; bcur[ss][1] = bnxt[ss][1];
                bcur[ss][2] = bnxt[ss][2]; bcur[ss][3] = bnxt[ss][3];
                facur[ss] = fanxt[ss]; fbcur[ss] = fbnxt[ss];
            }
        }
    }

    // ---- denominator: lanes l, l+16, l+32, l+48 share a row ----
    sacc += __shfl_xor(sacc, 16);
    sacc += __shfl_xor(sacc, 32);
    if (lane < 16) dred[wv][lane] = sacc;

    // ---- acc tree-reduce across waves; red aliases dead tile LDS ----
    f32x4* red = (f32x4*)smem;    // [2][256], 8 KB
    __syncthreads();
    if (wv >= 2) {
        #pragma unroll
        for (int cg = 0; cg < 4; ++cg) red[(wv - 2) * 256 + lane * 4 + cg] = acc[cg];
    }
    __syncthreads();
    if (wv < 2) {
        #pragma unroll
        for (int cg = 0; cg < 4; ++cg) acc[cg] += red[wv * 256 + lane * 4 + cg];
    }
    __syncthreads();
    if (wv == 1) {
        #pragma unroll
        for (int cg = 0; cg < 4; ++cg) red[lane * 4 + cg] = acc[cg];
    }
    __syncthreads();
    if (wv == 0) {
        #pragma unroll
        for (int cg = 0; cg < 4; ++cg) acc[cg] += red[lane * 4 + cg];
        // C/D layout: col = cg*16 + r, row = kg*4 + reg
        #pragma unroll
        for (int cg = 0; cg < 4; ++cg)
            #pragma unroll
            for (int rr = 0; rr < 4; ++rr)
                __builtin_nontemporal_store(acc[cg][rr],
                    &part[(size_t)bid * 1024 + (kg * 4 + rr) * FOUT + cg * 16 + r]);
        if (lane < 16)
            __builtin_nontemporal_store(
                dred[0][lane] + dred[1][lane] + dred[2][lane] + dred[3][lane],
                &pden[bid * 16 + lane]);
    }
}

// -------- kernel 3: combine KQ partials, normalize, ELU --------
__global__ __launch_bounds__(256) void k_fin(
        const float* __restrict__ part, const float* __restrict__ pden,
        float* __restrict__ out) {
    const int rg = blockIdx.x;
    const int t  = threadIdx.x;
    const int r  = t >> 4;
    const int c4 = (t & 15) * 4;

    float vx = 0.f, vy = 0.f, vz = 0.f, vw = 0.f;
    float den = 0.f;
    #pragma unroll
    for (int p = 0; p < KQ; ++p) {
        const int blk = rg * KQ + p;
        const f32x4 pv = __builtin_nontemporal_load(
            (const f32x4*)&part[(size_t)blk * 1024 + r * FOUT + c4]);
        vx += pv.x; vy += pv.y; vz += pv.z; vw += pv.w;
        den += __builtin_nontemporal_load(&pden[blk * 16 + r]);
    }
    den = fmaxf(den, 1e-30f);
    const float inv = __fdividef(1.f, den);
    f32x4 o;
    const float h0 = vx * inv; o.x = (h0 > 0.f) ? h0 : (__expf(h0) - 1.f);
    const float h1 = vy * inv; o.y = (h1 > 0.f) ? h1 : (__expf(h1) - 1.f);
    const float h2 = vz * inv; o.z = (h2 > 0.f) ? h2 : (__expf(h2) - 1.f);
    const float h3 = vw * inv; o.w = (h3 > 0.f) ? h3 : (__expf(h3) - 1.f);
    __builtin_nontemporal_store(o,
        (f32x4*)&out[(size_t)(rg * 16 + r) * FOUT + c4]);
}

extern "C" void kernel_launch(void* const* d_in, const int* in_sizes, int n_in,
                              void* d_out, int out_size, void* d_ws, size_t ws_size,
                              hipStream_t stream) {
    const float* X   = (const float*)d_in[0];
    const int*   adj = (const int*)d_in[1];
    const float* W   = (const float*)d_in[2];
    const float* a1  = (const float*)d_in[3];
    const float* a2  = (const float*)d_in[4];
    float* out = (float*)d_out;

    unsigned short* hb = (unsigned short*)d_ws;                   // 1 MB
    float* f1   = (float*)((char*)d_ws + (size_t)FOUT * N * 2);   // N floats
    float* f2   = f1 + N;                                         // N floats
    float* part = f2 + N;                                         // 4096*1024 floats
    float* pden = part + (size_t)(N / 16) * KQ * 1024;            // 4096*16 floats

    k_h   <<<N / 16, 256, 0, stream>>>(X, W, a1, a2, hb, f1, f2);
    k_attn<<<(N / 16) * KQ, 256, 0, stream>>>(adj, hb, f1, f2, part, pden);
    k_fin <<<N / 16, 256, 0, stream>>>(part, pden, out);
}